// Round 4
// baseline (722.437 us; speedup 1.0000x reference)
//
#include <hip/hip_runtime.h>

// OverISS-T  (input (2,4,512,1000) complex, 5 iterations)
// Multi-kernel, stream-ordered. Y state lives in d_out (Yr | Yi planes, final
// output layout). d_ws holds f-reduction scratch (~1.06 MB). W/H are dead
// state w.r.t. Y — skipped.
//
// Round 4: iter_c rewritten thread-major (n = lane*16 + s):
//  - all Y/sumf global traffic is float4 (64B per lane, 4KB per wave op)
//  - dereverb taps come from a 24-float per-lane register window (6 float4
//    loads per src) — zero LDS, zero ds_read, taps are register selects
//  - bounds via w=0 masking (clamped loads keep garbage finite; never stored)
//  - each stage's rank-1 update is fused into the next stage's accumulate
//    (28 slot-passes/iter instead of ~50)

constexpr int NCH = 4;
constexpr int NFQ = 512;
constexpr int NFR = 1000;
constexpr int NIT = 5;
constexpr float EPSV  = 1e-3f;
constexpr float LEPSV = 1e-5f;
constexpr float INVNF = 1.0f / 1000.0f;
constexpr float INVFN = 1.0f / (512.0f * 1000.0f);
constexpr size_t PLANE = 4096000;             // 2*4*512*1000
constexpr size_t CSTRIDE = (size_t)NFQ * NFR; // 512000

__device__ __forceinline__ void wave_sum(float& x) {
  #pragma unroll
  for (int m = 1; m < 64; m <<= 1) x += __shfl_xor(x, m);
}

// ---- Y0 = 0.999*X[c] + 0.001*sum_d X[d] ----
__global__ __launch_bounds__(256, 4)
void init_y(const float* __restrict__ Xr, const float* __restrict__ Xi,
            float* __restrict__ Y)
{
  const int bf = blockIdx.x, b = bf >> 9, f = bf & 511;
  const size_t base = ((size_t)b * NCH * NFQ + f) * NFR;
  #pragma unroll
  for (int k = 0; k < 4; ++k) {
    const int n = threadIdx.x + 256 * k;
    if (n < NFR) {
      float xr[4], xi[4];
      #pragma unroll
      for (int c = 0; c < 4; ++c) {
        xr[c] = Xr[base + (size_t)c * CSTRIDE + n];
        xi[c] = Xi[base + (size_t)c * CSTRIDE + n];
      }
      const float sr = xr[0] + xr[1] + xr[2] + xr[3];
      const float si = xi[0] + xi[1] + xi[2] + xi[3];
      #pragma unroll
      for (int c = 0; c < 4; ++c) {
        Y[base + (size_t)c * CSTRIDE + n]         = 0.999f * xr[c] + 0.001f * sr;
        Y[base + (size_t)c * CSTRIDE + n + PLANE] = 0.999f * xi[c] + 0.001f * si;
      }
    }
  }
}

// ---- B1: part[(b*4+c)*32+q][n] = sum_{f in 16q..16q+15} |Y[b,c,f,n]|^2 ----
__global__ __launch_bounds__(256, 4)
void partial_sumf(const float* __restrict__ Y, float* __restrict__ part)
{
  const int id = blockIdx.x;                 // 256 blocks: b | c | q
  const int q = id & 31, c = (id >> 5) & 3, b = id >> 7;
  const size_t base = (size_t)(b * NCH + c) * CSTRIDE + (size_t)q * 16 * NFR;
  float acc[4] = {0.f, 0.f, 0.f, 0.f};
  for (int ff = 0; ff < 16; ++ff) {
    #pragma unroll
    for (int k = 0; k < 4; ++k) {
      const int n = threadIdx.x + 256 * k;
      if (n < NFR) {
        const float r = Y[base + (size_t)ff * NFR + n];
        const float i = Y[base + (size_t)ff * NFR + n + PLANE];
        acc[k] = fmaf(r, r, acc[k]);
        acc[k] = fmaf(i, i, acc[k]);
      }
    }
  }
  #pragma unroll
  for (int k = 0; k < 4; ++k) {
    const int n = threadIdx.x + 256 * k;
    if (n < NFR) part[((size_t)(b * NCH + c) * 32 + q) * NFR + n] = acc[k];
  }
}

// ---- B2: sumf[b*4000 + c*1000 + n] = sum_q part ----
__global__ __launch_bounds__(256, 4)
void finish_sumf(const float* __restrict__ part, float* __restrict__ sumf)
{
  const int o = blockIdx.x * 256 + threadIdx.x;
  if (o < 8000) {
    const int b = o / 4000;
    const int rem = o - b * 4000;
    const int c = rem / 1000;
    const int n = rem - c * 1000;
    const float* p = part + ((size_t)(b * NCH + c) * 32) * NFR + n;
    float s = 0.f;
    for (int q = 0; q < 32; ++q) s += p[(size_t)q * NFR];
    sumf[o] = s;
  }
}

// ---- stage C: one full iteration for one (b,f) slice — one wave, zero LDS ----
__global__ __launch_bounds__(64, 1)
void iter_c(const float* __restrict__ Xr, const float* __restrict__ Xi,
            float* __restrict__ Y, const float* __restrict__ sumf)
{
  const int lane = threadIdx.x;
  const int bf = blockIdx.x, b = bf >> 9, f = bf & 511;
  const size_t base = ((size_t)b * NCH * NFQ + f) * NFR;
  const int n0 = lane * 16;           // this thread owns frames n0..n0+15

  // ---- load Y (thread-major float4, clamped) ----
  float yre[16][4], yim[16][4];
  #pragma unroll
  for (int c = 0; c < 4; ++c) {
    const float* pr = Y + base + (size_t)c * CSTRIDE;
    const float* pi = pr + PLANE;
    #pragma unroll
    for (int q = 0; q < 4; ++q) {
      const int nq = min(n0 + 4 * q, 996);
      const float4 vr = *(const float4*)(pr + nq);
      const float4 vi = *(const float4*)(pi + nq);
      yre[4*q+0][c] = vr.x; yre[4*q+1][c] = vr.y;
      yre[4*q+2][c] = vr.z; yre[4*q+3][c] = vr.w;
      yim[4*q+0][c] = vi.x; yim[4*q+1][c] = vi.y;
      yim[4*q+2][c] = vi.z; yim[4*q+3][c] = vi.w;
    }
  }

  // ---- sumf -> g, weights w; normalize y (invalid slots get w = 0) ----
  float w[16][4];
  {
    float sfr[16][4];
    const float* sfb = sumf + b * 4000;
    #pragma unroll
    for (int c = 0; c < 4; ++c) {
      #pragma unroll
      for (int q = 0; q < 4; ++q) {
        const int nq = min(n0 + 4 * q, 996);
        const float4 sv = *(const float4*)(sfb + c * 1000 + nq);
        sfr[4*q+0][c] = sv.x; sfr[4*q+1][c] = sv.y;
        sfr[4*q+2][c] = sv.z; sfr[4*q+3][c] = sv.w;
      }
    }
    float gp[4] = {0.f, 0.f, 0.f, 0.f};
    #pragma unroll
    for (int s = 0; s < 16; ++s) {
      const bool valid = (n0 + s) < NFR;
      #pragma unroll
      for (int c = 0; c < 4; ++c) gp[c] += valid ? sfr[s][c] : 0.f;
    }
    #pragma unroll
    for (int c = 0; c < 4; ++c) wave_sum(gp[c]);

    float g[4], invgs[4];
    #pragma unroll
    for (int c = 0; c < 4; ++c) {
      g[c]     = fmaxf(gp[c] * INVFN, EPSV);
      invgs[c] = 1.0f / sqrtf(g[c]);     // sqrt(g) >= sqrt(1e-3) > EPS
    }
    #pragma unroll
    for (int s = 0; s < 16; ++s) {
      const bool valid = (n0 + s) < NFR;
      #pragma unroll
      for (int c = 0; c < 4; ++c) {
        w[s][c] = valid ? g[c] / fmaxf(2.0f * sqrtf(sfr[s][c]), LEPSV) : 0.f;
        yre[s][c] *= invgs[c];
        yim[s][c] *= invgs[c];
      }
    }
  }

  float p[12], vr_[4], vi_[4];

  // ---- source stage 0 (plain accumulate, z = y[.][0]) ----
  #pragma unroll
  for (int j = 0; j < 12; ++j) p[j] = 0.f;
  #pragma unroll
  for (int s = 0; s < 16; ++s) {
    const float zr = yre[s][0], zi = yim[s][0];
    const float zz = zr * zr + zi * zi;
    #pragma unroll
    for (int c = 0; c < 4; ++c) {
      const float wk = w[s][c];
      p[8+c] = fmaf(wk, zz, p[8+c]);
      p[c]   = fmaf(wk, yre[s][c]*zr + yim[s][c]*zi, p[c]);
      p[4+c] = fmaf(wk, yim[s][c]*zr - yre[s][c]*zi, p[4+c]);
    }
  }
  #pragma unroll
  for (int j = 0; j < 12; ++j) wave_sum(p[j]);
  {
    float vd[4];
    #pragma unroll
    for (int c = 0; c < 4; ++c) vd[c] = fmaxf(p[8+c] * INVNF, EPSV);
    #pragma unroll
    for (int c = 0; c < 4; ++c) {
      const float inv = INVNF / vd[c];
      vr_[c] = p[c] * inv;  vi_[c] = p[4+c] * inv;
    }
    vr_[0] = 1.0f - 1.0f / sqrtf(vd[0]);  vi_[0] = 0.0f;
  }

  // ---- source stages 1..3: fused (apply prev update, accumulate new) ----
  #pragma unroll
  for (int src = 1; src < 4; ++src) {
    #pragma unroll
    for (int j = 0; j < 12; ++j) p[j] = 0.f;
    #pragma unroll
    for (int s = 0; s < 16; ++s) {
      const float ur = yre[s][src-1], ui = yim[s][src-1];   // prev z snapshot
      #pragma unroll
      for (int c = 0; c < 4; ++c) {
        yre[s][c] -= vr_[c]*ur - vi_[c]*ui;
        yim[s][c] -= vr_[c]*ui + vi_[c]*ur;
      }
      const float zr = yre[s][src], zi = yim[s][src];       // updated value
      const float zz = zr * zr + zi * zi;
      #pragma unroll
      for (int c = 0; c < 4; ++c) {
        const float wk = w[s][c];
        p[8+c] = fmaf(wk, zz, p[8+c]);
        p[c]   = fmaf(wk, yre[s][c]*zr + yim[s][c]*zi, p[c]);
        p[4+c] = fmaf(wk, yim[s][c]*zr - yre[s][c]*zi, p[4+c]);
      }
    }
    #pragma unroll
    for (int j = 0; j < 12; ++j) wave_sum(p[j]);
    float vd[4];
    #pragma unroll
    for (int c = 0; c < 4; ++c) vd[c] = fmaxf(p[8+c] * INVNF, EPSV);
    #pragma unroll
    for (int c = 0; c < 4; ++c) {
      const float inv = INVNF / vd[c];
      vr_[c] = p[c] * inv;  vi_[c] = p[4+c] * inv;
    }
    vr_[src] = 1.0f - 1.0f / sqrtf(vd[src]);  vi_[src] = 0.0f;
  }

  // ---- dereverb: per src a 24-float register window X[n0-8 .. n0+15] ----
  // z for tap t: xw[s + t + 2]  (xw[j] = X[n0 - 8 + j]; lane0's j<8 zeroed)
  float xwr[24], xwi[24];
  #pragma unroll
  for (int src4 = 0; src4 < 4; ++src4) {
    const float* pxr = Xr + base + (size_t)src4 * CSTRIDE;
    const float* pxi = Xi + base + (size_t)src4 * CSTRIDE;
    #pragma unroll
    for (int q = 0; q < 6; ++q) {
      const int nq = min(max(n0 - 8 + 4 * q, 0), 996);
      const float4 ar = *(const float4*)(pxr + nq);
      const float4 ai = *(const float4*)(pxi + nq);
      xwr[4*q+0] = ar.x; xwr[4*q+1] = ar.y; xwr[4*q+2] = ar.z; xwr[4*q+3] = ar.w;
      xwi[4*q+0] = ai.x; xwi[4*q+1] = ai.y; xwi[4*q+2] = ai.z; xwi[4*q+3] = ai.w;
    }
    if (lane == 0) {
      #pragma unroll
      for (int j = 0; j < 8; ++j) { xwr[j] = 0.f; xwi[j] = 0.f; }
    }

    #pragma unroll
    for (int tap = 0; tap < 5; ++tap) {
      #pragma unroll
      for (int j = 0; j < 12; ++j) p[j] = 0.f;
      #pragma unroll
      for (int s = 0; s < 16; ++s) {
        if (tap == 0 && src4 == 0) {           // pending update from src=3
          const float ur = yre[s][3], ui = yim[s][3];
          #pragma unroll
          for (int c = 0; c < 4; ++c) {
            yre[s][c] -= vr_[c]*ur - vi_[c]*ui;
            yim[s][c] -= vr_[c]*ui + vi_[c]*ur;
          }
        } else if (tap > 0) {                  // pending update from prev tap
          const float ur = xwr[s+tap+1], ui = xwi[s+tap+1];
          #pragma unroll
          for (int c = 0; c < 4; ++c) {
            yre[s][c] -= vr_[c]*ur - vi_[c]*ui;
            yim[s][c] -= vr_[c]*ui + vi_[c]*ur;
          }
        }
        const float zr = xwr[s+tap+2], zi = xwi[s+tap+2];
        const float zz = zr * zr + zi * zi;
        #pragma unroll
        for (int c = 0; c < 4; ++c) {
          const float wk = w[s][c];
          p[8+c] = fmaf(wk, zz, p[8+c]);
          p[c]   = fmaf(wk, yre[s][c]*zr + yim[s][c]*zi, p[c]);
          p[4+c] = fmaf(wk, yim[s][c]*zr - yre[s][c]*zi, p[4+c]);
        }
      }
      #pragma unroll
      for (int j = 0; j < 12; ++j) wave_sum(p[j]);
      #pragma unroll
      for (int c = 0; c < 4; ++c) {            // dereverb: no inv_nf (matches ref)
        const float inv = 1.0f / fmaxf(p[8+c], EPSV);
        vr_[c] = p[c] * inv;  vi_[c] = p[4+c] * inv;
      }
    }

    if (src4 < 3) {                            // standalone tap-4 update
      #pragma unroll
      for (int s = 0; s < 16; ++s) {
        const float ur = xwr[s+6], ui = xwi[s+6];
        #pragma unroll
        for (int c = 0; c < 4; ++c) {
          yre[s][c] -= vr_[c]*ur - vi_[c]*ui;
          yim[s][c] -= vr_[c]*ui + vi_[c]*ur;
        }
      }
    }
  }

  // ---- final: apply last update (src4=3 tap4) and write back ----
  #pragma unroll
  for (int s = 0; s < 16; ++s) {
    const float ur = xwr[s+6], ui = xwi[s+6];
    #pragma unroll
    for (int c = 0; c < 4; ++c) {
      yre[s][c] -= vr_[c]*ur - vi_[c]*ui;
      yim[s][c] -= vr_[c]*ui + vi_[c]*ur;
    }
  }
  #pragma unroll
  for (int c = 0; c < 4; ++c) {
    float* pr = Y + base + (size_t)c * CSTRIDE;
    float* pi = pr + PLANE;
    #pragma unroll
    for (int q = 0; q < 4; ++q) {
      const int nq = n0 + 4 * q;
      if (nq < NFR) {     // 1000 % 4 == 0 -> whole quad valid
        *(float4*)(pr + nq) = make_float4(yre[4*q+0][c], yre[4*q+1][c],
                                          yre[4*q+2][c], yre[4*q+3][c]);
        *(float4*)(pi + nq) = make_float4(yim[4*q+0][c], yim[4*q+1][c],
                                          yim[4*q+2][c], yim[4*q+3][c]);
      }
    }
  }
}

extern "C" void kernel_launch(void* const* d_in, const int* in_sizes, int n_in,
                              void* d_out, int out_size, void* d_ws, size_t ws_size,
                              hipStream_t stream)
{
  const float* Xr = (const float*)d_in[0];
  const float* Xi = (const float*)d_in[1];
  float* Y = (float*)d_out;                 // Yr | Yi, final layout
  float* part = (float*)d_ws;               // 256,000 floats
  float* sumf = part + 256000;              // 8,000 floats

  init_y<<<1024, 256, 0, stream>>>(Xr, Xi, Y);
  for (int it = 0; it < NIT; ++it) {
    partial_sumf<<<256, 256, 0, stream>>>(Y, part);
    finish_sumf<<<32, 256, 0, stream>>>(part, sumf);
    iter_c<<<1024, 64, 0, stream>>>(Xr, Xi, Y, sumf);
  }
}

// Round 6
// 668.239 us; speedup vs baseline: 1.0811x; 1.0811x over previous
//
#include <hip/hip_runtime.h>

// OverISS-T  (input (2,4,512,1000) complex, 5 iterations)
// Multi-kernel, stream-ordered. Y state lives in d_out (Yr | Yi planes, final
// output layout). W/H are dead state w.r.t. Y — skipped.
//
// Round 6 (= round 5 design, compile fix + dedup):
//  - chunked lane-major mapping n = 256q + 4*lane + e -> all Y/sumf global
//    I/O is aligned float4; validity is per-chunk uniform (w=0 masking)
//  - zero-padded LDS X ([8+n], front+tail zeroed): dereverb tap reads are
//    ds_read at compile-time immediate offsets, no bounds logic at all
//  - rsqrt/rcp fast intrinsics in weight & v computation (4x abs headroom)
//  - |Y|^2 plane written during iter_c/init_y epilogue (d_ws), reduced over
//    f by 2 coalesced kernels; falls back to Y-reading reduction if ws small.

constexpr int NCH = 4;
constexpr int NFQ = 512;
constexpr int NFR = 1000;
constexpr int NIT = 5;
constexpr float EPSV  = 1e-3f;
constexpr float INVNF = 1.0f / 1000.0f;
constexpr float INVFN = 1.0f / (512.0f * 1000.0f);
constexpr size_t PLANE = 4096000;             // 2*4*512*1000
constexpr size_t CSTRIDE = (size_t)NFQ * NFR; // 512000

__device__ __forceinline__ void wave_sum(float& x) {
  #pragma unroll
  for (int m = 1; m < 64; m <<= 1) x += __shfl_xor(x, m);
}
__device__ __forceinline__ float fast_rcp(float x)  { return __builtin_amdgcn_rcpf(x); }
__device__ __forceinline__ float fast_rsq(float x)  { return __builtin_amdgcn_rsqf(x); }

// ---- init: Y0 = 0.999*X[c] + 0.001*sum_d X[d];  optional |Y0|^2 plane ----
__global__ __launch_bounds__(256, 4)
void init_y(const float* __restrict__ Xr, const float* __restrict__ Xi,
            float* __restrict__ Y, float* __restrict__ mag)
{
  const int bf = blockIdx.x, b = bf >> 9, f = bf & 511;
  const size_t base = ((size_t)b * NCH * NFQ + f) * NFR;
  const int tid = threadIdx.x;
  if (tid < 250) {
    const int nq = 4 * tid;
    float4 xr[4], xi[4];
    #pragma unroll
    for (int c = 0; c < 4; ++c) {
      xr[c] = *(const float4*)(Xr + base + (size_t)c * CSTRIDE + nq);
      xi[c] = *(const float4*)(Xi + base + (size_t)c * CSTRIDE + nq);
    }
    float4 sr, si;
    sr.x = xr[0].x+xr[1].x+xr[2].x+xr[3].x;  si.x = xi[0].x+xi[1].x+xi[2].x+xi[3].x;
    sr.y = xr[0].y+xr[1].y+xr[2].y+xr[3].y;  si.y = xi[0].y+xi[1].y+xi[2].y+xi[3].y;
    sr.z = xr[0].z+xr[1].z+xr[2].z+xr[3].z;  si.z = xi[0].z+xi[1].z+xi[2].z+xi[3].z;
    sr.w = xr[0].w+xr[1].w+xr[2].w+xr[3].w;  si.w = xi[0].w+xi[1].w+xi[2].w+xi[3].w;
    #pragma unroll
    for (int c = 0; c < 4; ++c) {
      float4 yr, yi;
      yr.x = 0.999f*xr[c].x + 0.001f*sr.x;  yi.x = 0.999f*xi[c].x + 0.001f*si.x;
      yr.y = 0.999f*xr[c].y + 0.001f*sr.y;  yi.y = 0.999f*xi[c].y + 0.001f*si.y;
      yr.z = 0.999f*xr[c].z + 0.001f*sr.z;  yi.z = 0.999f*xi[c].z + 0.001f*si.z;
      yr.w = 0.999f*xr[c].w + 0.001f*sr.w;  yi.w = 0.999f*xi[c].w + 0.001f*si.w;
      *(float4*)(Y + base + (size_t)c * CSTRIDE + nq)         = yr;
      *(float4*)(Y + base + (size_t)c * CSTRIDE + nq + PLANE) = yi;
      if (mag) {
        float4 m;
        m.x = yr.x*yr.x + yi.x*yi.x;  m.y = yr.y*yr.y + yi.y*yi.y;
        m.z = yr.z*yr.z + yi.z*yi.z;  m.w = yr.w*yr.w + yi.w*yi.w;
        *(float4*)(mag + ((size_t)((b*4+c)*NFQ) + f) * NFR + nq) = m;
      }
    }
  }
}

// ---- mag-plane reduction over f: stage 1 (32-f chunks) ----
__global__ __launch_bounds__(256, 4)
void partial_mag(const float* __restrict__ mag, float* __restrict__ part2)
{
  const int id = blockIdx.x;                  // 128 blocks: b | c | k
  const int k = id & 15, c = (id >> 4) & 3, b = id >> 6;
  const int tid = threadIdx.x;
  if (tid < 250) {
    const int nq = 4 * tid;
    const float* base = mag + ((size_t)((b*4+c)*NFQ + k*32)) * NFR + nq;
    float4 acc = make_float4(0.f, 0.f, 0.f, 0.f);
    for (int ff = 0; ff < 32; ++ff) {
      const float4 v = *(const float4*)(base + (size_t)ff * NFR);
      acc.x += v.x; acc.y += v.y; acc.z += v.z; acc.w += v.w;
    }
    *(float4*)(part2 + ((size_t)((b*4+c)*16 + k)) * NFR + nq) = acc;
  }
}

// ---- mag-plane reduction stage 2 ----
__global__ __launch_bounds__(256, 4)
void finish_mag(const float* __restrict__ part2, float* __restrict__ sumf)
{
  const int t = blockIdx.x * 256 + threadIdx.x;   // 8 blocks, 2000 quads
  if (t < 2000) {
    const int b = t / 1000, r = t - 1000 * b;
    const int c = r / 250,  qn = r - 250 * c;
    const float* base = part2 + ((size_t)((b*4+c)*16)) * NFR + 4*qn;
    float4 acc = make_float4(0.f, 0.f, 0.f, 0.f);
    #pragma unroll
    for (int k = 0; k < 16; ++k) {
      const float4 v = *(const float4*)(base + (size_t)k * NFR);
      acc.x += v.x; acc.y += v.y; acc.z += v.z; acc.w += v.w;
    }
    *(float4*)(sumf + (size_t)b*4000 + c*1000 + 4*qn) = acc;
  }
}

// ---- legacy sumf path (reads Y) — fallback when ws is small ----
__global__ __launch_bounds__(256, 4)
void partial_sumf(const float* __restrict__ Y, float* __restrict__ part)
{
  const int id = blockIdx.x;                 // 256 blocks: b | c | q
  const int q = id & 31, c = (id >> 5) & 3, b = id >> 7;
  const size_t base = (size_t)(b * NCH + c) * CSTRIDE + (size_t)q * 16 * NFR;
  float acc[4] = {0.f, 0.f, 0.f, 0.f};
  for (int ff = 0; ff < 16; ++ff) {
    #pragma unroll
    for (int k = 0; k < 4; ++k) {
      const int n = threadIdx.x + 256 * k;
      if (n < NFR) {
        const float r = Y[base + (size_t)ff * NFR + n];
        const float i = Y[base + (size_t)ff * NFR + n + PLANE];
        acc[k] = fmaf(r, r, acc[k]);
        acc[k] = fmaf(i, i, acc[k]);
      }
    }
  }
  #pragma unroll
  for (int k = 0; k < 4; ++k) {
    const int n = threadIdx.x + 256 * k;
    if (n < NFR) part[((size_t)(b * NCH + c) * 32 + q) * NFR + n] = acc[k];
  }
}
__global__ __launch_bounds__(256, 4)
void finish_sumf(const float* __restrict__ part, float* __restrict__ sumf)
{
  const int o = blockIdx.x * 256 + threadIdx.x;
  if (o < 8000) {
    const int b = o / 4000;
    const int rem = o - b * 4000;
    const int c = rem / 1000;
    const int n = rem - c * 1000;
    const float* p = part + ((size_t)(b * NCH + c) * 32) * NFR + n;
    float s = 0.f;
    for (int q = 0; q < 32; ++q) s += p[(size_t)q * NFR];
    sumf[o] = s;
  }
}

// ---- stage C: one full iteration for one (b,f) slice — one wave ----
// slot s = 4q+e owns frame n(s) = 256q + 4*lane + e ; chunk 3 invalid for lane>57
__global__ __launch_bounds__(64, 1)
void iter_c(const float* __restrict__ Xr, const float* __restrict__ Xi,
            float* __restrict__ Y, const float* __restrict__ sumf,
            float* __restrict__ mag)
{
  __shared__ float xpad[2][4][1032];   // [re/im][c][8 + n + 24], 33 KB

  const int lane = threadIdx.x;
  const int bf = blockIdx.x, b = bf >> 9, f = bf & 511;
  const size_t base = ((size_t)b * NCH * NFQ + f) * NFR;
  const bool c3ok = (lane <= 57);           // chunk-3 validity (uniform over e)

  // ---- zero LDS pads (front 8 + tail 24 per array; 8 arrays x 32 slots) ----
  #pragma unroll
  for (int j = 0; j < 4; ++j) {
    const int jj = lane + 64 * j;           // 0..255
    const int a = jj >> 5, t = jj & 31;
    (&xpad[0][0][0])[a * 1032 + (t < 8 ? t : 1000 + t)] = 0.f;
  }
  // ---- stage X into LDS (float4 both sides) ----
  #pragma unroll
  for (int r = 0; r < 2; ++r) {
    const float* src = (r == 0 ? Xr : Xi);
    #pragma unroll
    for (int c = 0; c < 4; ++c) {
      for (int q = lane; q < 250; q += 64) {
        const float4 v = *(const float4*)(src + base + (size_t)c * CSTRIDE + 4 * q);
        *(float4*)(&xpad[r][c][8 + 4 * q]) = v;
      }
    }
  }
  // single wave: ds_write->ds_read ordering via lgkmcnt, no barrier needed.

  // ---- sumf -> g, invgs, weights w (one pass) ----
  float w[16][4], invgs[4];
  {
    float sfr[16][4];
    const float* sfb = sumf + b * 4000;
    #pragma unroll
    for (int c = 0; c < 4; ++c) {
      #pragma unroll
      for (int q = 0; q < 4; ++q) {
        const int nq = (q < 3) ? (256 * q + 4 * lane) : min(768 + 4 * lane, 996);
        const float4 sv = *(const float4*)(sfb + c * 1000 + nq);
        sfr[4*q+0][c] = sv.x; sfr[4*q+1][c] = sv.y;
        sfr[4*q+2][c] = sv.z; sfr[4*q+3][c] = sv.w;
      }
    }
    float gp[4] = {0.f, 0.f, 0.f, 0.f};
    #pragma unroll
    for (int s = 0; s < 16; ++s) {
      const bool valid = (s < 12) || c3ok;
      #pragma unroll
      for (int c = 0; c < 4; ++c) gp[c] += valid ? sfr[s][c] : 0.f;
    }
    #pragma unroll
    for (int c = 0; c < 4; ++c) wave_sum(gp[c]);

    float g[4];
    #pragma unroll
    for (int c = 0; c < 4; ++c) {
      g[c]     = fmaxf(gp[c] * INVFN, EPSV);
      invgs[c] = fast_rsq(g[c]);           // sqrt(g) >= sqrt(1e-3) > EPS
    }
    // w = g / max(2*sqrt(s), 1e-5)  ==  g * min(0.5*rsqrt(s), 1e5)
    #pragma unroll
    for (int s = 0; s < 16; ++s) {
      const bool valid = (s < 12) || c3ok;
      #pragma unroll
      for (int c = 0; c < 4; ++c)
        w[s][c] = valid ? g[c] * fminf(0.5f * fast_rsq(sfr[s][c]), 1e5f) : 0.f;
    }
  }

  // ---- load Y (aligned float4, chunk-3 clamped) and normalize ----
  float yre[16][4], yim[16][4];
  #pragma unroll
  for (int c = 0; c < 4; ++c) {
    const float* pr = Y + base + (size_t)c * CSTRIDE;
    const float* pi = pr + PLANE;
    #pragma unroll
    for (int q = 0; q < 4; ++q) {
      const int nq = (q < 3) ? (256 * q + 4 * lane) : min(768 + 4 * lane, 996);
      const float4 vr = *(const float4*)(pr + nq);
      const float4 vi = *(const float4*)(pi + nq);
      yre[4*q+0][c] = vr.x * invgs[c]; yre[4*q+1][c] = vr.y * invgs[c];
      yre[4*q+2][c] = vr.z * invgs[c]; yre[4*q+3][c] = vr.w * invgs[c];
      yim[4*q+0][c] = vi.x * invgs[c]; yim[4*q+1][c] = vi.y * invgs[c];
      yim[4*q+2][c] = vi.z * invgs[c]; yim[4*q+3][c] = vi.w * invgs[c];
    }
  }

  float p[12], vr_[4], vi_[4];

  // ----- 4 source stages -----
  #pragma unroll
  for (int src = 0; src < 4; ++src) {
    #pragma unroll
    for (int j = 0; j < 12; ++j) p[j] = 0.f;
    #pragma unroll
    for (int s = 0; s < 16; ++s) {
      const float zr = yre[s][src], zi = yim[s][src];
      const float zz = zr * zr + zi * zi;
      #pragma unroll
      for (int c = 0; c < 4; ++c) {
        const float wk = w[s][c];
        p[8+c] = fmaf(wk, zz, p[8+c]);
        p[c]   = fmaf(wk, yre[s][c]*zr + yim[s][c]*zi, p[c]);
        p[4+c] = fmaf(wk, yim[s][c]*zr - yre[s][c]*zi, p[4+c]);
      }
    }
    #pragma unroll
    for (int j = 0; j < 12; ++j) wave_sum(p[j]);

    float vd[4];
    #pragma unroll
    for (int c = 0; c < 4; ++c) vd[c] = fmaxf(p[8+c] * INVNF, EPSV);
    #pragma unroll
    for (int c = 0; c < 4; ++c) {
      const float inv = INVNF * fast_rcp(vd[c]);
      vr_[c] = p[c] * inv;  vi_[c] = p[4+c] * inv;
    }
    vr_[src] = 1.0f - fast_rsq(vd[src]);  vi_[src] = 0.0f;

    #pragma unroll
    for (int s = 0; s < 16; ++s) {
      const float zr = yre[s][src], zi = yim[s][src];
      #pragma unroll
      for (int c = 0; c < 4; ++c) {
        yre[s][c] -= vr_[c]*zr - vi_[c]*zi;
        yim[s][c] -= vr_[c]*zi + vi_[c]*zr;
      }
    }
  }

  // ----- 20 dereverb stages: z = X[src][n + tap - 6] from padded LDS -----
  #pragma unroll
  for (int src = 0; src < 4; ++src) {
    const float* pxr = &xpad[0][src][0];
    const float* pxi = &xpad[1][src][0];
    const int ib = 4 * lane;
    #pragma unroll
    for (int tap = 0; tap < 5; ++tap) {
      const int off = 8 + tap - 6;          // pad-adjusted base offset (2..6)
      float zr[16], zi[16];
      #pragma unroll
      for (int q = 0; q < 4; ++q) {
        #pragma unroll
        for (int e = 0; e < 4; ++e) {
          zr[4*q+e] = pxr[ib + 256*q + e + off];
          zi[4*q+e] = pxi[ib + 256*q + e + off];
        }
      }

      #pragma unroll
      for (int j = 0; j < 12; ++j) p[j] = 0.f;
      #pragma unroll
      for (int s = 0; s < 16; ++s) {
        const float zz = zr[s]*zr[s] + zi[s]*zi[s];
        #pragma unroll
        for (int c = 0; c < 4; ++c) {
          const float wk = w[s][c];
          p[8+c] = fmaf(wk, zz, p[8+c]);
          p[c]   = fmaf(wk, yre[s][c]*zr[s] + yim[s][c]*zi[s], p[c]);
          p[4+c] = fmaf(wk, yim[s][c]*zr[s] - yre[s][c]*zi[s], p[4+c]);
        }
      }
      #pragma unroll
      for (int j = 0; j < 12; ++j) wave_sum(p[j]);

      #pragma unroll
      for (int c = 0; c < 4; ++c) {         // dereverb: no inv_nf (matches ref)
        const float inv = fast_rcp(fmaxf(p[8+c], EPSV));
        vr_[c] = p[c] * inv;  vi_[c] = p[4+c] * inv;
      }
      #pragma unroll
      for (int s = 0; s < 16; ++s) {
        #pragma unroll
        for (int c = 0; c < 4; ++c) {
          yre[s][c] -= vr_[c]*zr[s] - vi_[c]*zi[s];
          yim[s][c] -= vr_[c]*zi[s] + vi_[c]*zr[s];
        }
      }
    }
  }

  // ---- write back Y (+ optional |Y|^2 plane) ----
  #pragma unroll
  for (int c = 0; c < 4; ++c) {
    float* pr = Y + base + (size_t)c * CSTRIDE;
    float* pi = pr + PLANE;
    float* pm = mag ? (mag + ((size_t)((b*4+c)*NFQ) + f) * NFR) : nullptr;
    #pragma unroll
    for (int q = 0; q < 4; ++q) {
      if (q < 3 || c3ok) {
        const int nq = 256 * q + 4 * lane;
        const float4 vr = make_float4(yre[4*q+0][c], yre[4*q+1][c],
                                      yre[4*q+2][c], yre[4*q+3][c]);
        const float4 vi = make_float4(yim[4*q+0][c], yim[4*q+1][c],
                                      yim[4*q+2][c], yim[4*q+3][c]);
        *(float4*)(pr + nq) = vr;
        *(float4*)(pi + nq) = vi;
        if (pm) {
          float4 m;
          m.x = vr.x*vr.x + vi.x*vi.x;  m.y = vr.y*vr.y + vi.y*vi.y;
          m.z = vr.z*vr.z + vi.z*vi.z;  m.w = vr.w*vr.w + vi.w*vi.w;
          *(float4*)(pm + nq) = m;
        }
      }
    }
  }
}

extern "C" void kernel_launch(void* const* d_in, const int* in_sizes, int n_in,
                              void* d_out, int out_size, void* d_ws, size_t ws_size,
                              hipStream_t stream)
{
  const float* Xr = (const float*)d_in[0];
  const float* Xi = (const float*)d_in[1];
  float* Y = (float*)d_out;                 // Yr | Yi, final layout

  const bool big_ws = ws_size >= (size_t)(4096000 + 128000 + 8000) * 4;
  if (big_ws) {
    float* mag   = (float*)d_ws;            // 4,096,000 floats
    float* part2 = mag + 4096000;           // 128,000
    float* sumf  = part2 + 128000;          // 8,000
    init_y<<<1024, 256, 0, stream>>>(Xr, Xi, Y, mag);
    for (int it = 0; it < NIT; ++it) {
      partial_mag<<<128, 256, 0, stream>>>(mag, part2);
      finish_mag<<<8, 256, 0, stream>>>(part2, sumf);
      // last iteration: nobody consumes mag afterwards -> skip the extra write
      iter_c<<<1024, 64, 0, stream>>>(Xr, Xi, Y, sumf,
                                      (it < NIT - 1) ? mag : nullptr);
    }
  } else {
    float* part = (float*)d_ws;             // 256,000 floats
    float* sumf = part + 256000;            // 8,000
    init_y<<<1024, 256, 0, stream>>>(Xr, Xi, Y, nullptr);
    for (int it = 0; it < NIT; ++it) {
      partial_sumf<<<256, 256, 0, stream>>>(Y, part);
      finish_sumf<<<32, 256, 0, stream>>>(part, sumf);
      iter_c<<<1024, 64, 0, stream>>>(Xr, Xi, Y, sumf, nullptr);
    }
  }
}

// Round 7
// 429.967 us; speedup vs baseline: 1.6802x; 1.5542x over previous
//
#include <hip/hip_runtime.h>

// OverISS-T  (input (2,4,512,1000) complex, 5 iterations)
// Multi-kernel, stream-ordered. Y state lives in d_out (Yr | Yi planes, final
// output layout). d_ws holds f-reduction scratch. W/H are dead state — skipped.
//
// Round 7 (base = R3 structure, which measured 0 bank conflicts / 33MB fetch):
//  - iter_c: 2 waves per block (128 thr, 8 frame-slots/thread) -> 8 waves/CU
//    = 2 waves/SIMD for latency hiding; per-wave work halved.
//  - per-stage reduction: 6-step DPP v_add (no DS butterflies) + readlane,
//    cross-wave combine via parity-double-buffered LDS, ONE barrier/stage.
//  - fast rcp/rsqrt for v and weight computation.
//  - source stages skip the dead p[src], p[4+src] numerators.

constexpr int NCH = 4;
constexpr int NFQ = 512;
constexpr int NFR = 1000;
constexpr int NIT = 5;
constexpr float EPSV  = 1e-3f;
constexpr float INVNF = 1.0f / 1000.0f;
constexpr float INVFN = 1.0f / (512.0f * 1000.0f);
constexpr size_t PLANE = 4096000;             // 2*4*512*1000
constexpr size_t CSTRIDE = (size_t)NFQ * NFR; // 512000

__device__ __forceinline__ float fast_rcp(float x) { return __builtin_amdgcn_rcpf(x); }
__device__ __forceinline__ float fast_rsq(float x) { return __builtin_amdgcn_rsqf(x); }

// x + dpp_mov(x): DPP-based 64-lane sum. After 6 steps lanes 48..63 hold the
// total; readlane(63) broadcasts it (uniform).
template <int CTRL>
__device__ __forceinline__ float dpp_add(float x) {
  return x + __int_as_float(__builtin_amdgcn_update_dpp(
      0, __float_as_int(x), CTRL, 0xF, 0xF, true));
}
__device__ __forceinline__ float wave_red(float x) {
  x = dpp_add<0xB1>(x);    // quad_perm [1,0,3,2]
  x = dpp_add<0x4E>(x);    // quad_perm [2,3,0,1]
  x = dpp_add<0x141>(x);   // row_half_mirror
  x = dpp_add<0x140>(x);   // row_mirror
  x = dpp_add<0x142>(x);   // row_bcast15
  x = dpp_add<0x143>(x);   // row_bcast31
  return __int_as_float(__builtin_amdgcn_readlane(__float_as_int(x), 63));
}

// ---- Y0 = 0.999*X[c] + 0.001*sum_d X[d]  (W0 = max(I,0.001), H = 0) ----
__global__ __launch_bounds__(256, 4)
void init_y(const float* __restrict__ Xr, const float* __restrict__ Xi,
            float* __restrict__ Y)
{
  const int bf = blockIdx.x, b = bf >> 9, f = bf & 511;
  const size_t base = ((size_t)b * NCH * NFQ + f) * NFR;
  #pragma unroll
  for (int k = 0; k < 4; ++k) {
    const int n = threadIdx.x + 256 * k;
    if (n < NFR) {
      float xr[4], xi[4];
      #pragma unroll
      for (int c = 0; c < 4; ++c) {
        xr[c] = Xr[base + (size_t)c * CSTRIDE + n];
        xi[c] = Xi[base + (size_t)c * CSTRIDE + n];
      }
      const float sr = xr[0] + xr[1] + xr[2] + xr[3];
      const float si = xi[0] + xi[1] + xi[2] + xi[3];
      #pragma unroll
      for (int c = 0; c < 4; ++c) {
        Y[base + (size_t)c * CSTRIDE + n]         = 0.999f * xr[c] + 0.001f * sr;
        Y[base + (size_t)c * CSTRIDE + n + PLANE] = 0.999f * xi[c] + 0.001f * si;
      }
    }
  }
}

// ---- B1: part[(b*4+c)*32+q][n] = sum_{f in 16q..16q+15} |Y[b,c,f,n]|^2 ----
__global__ __launch_bounds__(256, 4)
void partial_sumf(const float* __restrict__ Y, float* __restrict__ part)
{
  const int id = blockIdx.x;                 // 256 blocks: b | c | q
  const int q = id & 31, c = (id >> 5) & 3, b = id >> 7;
  const size_t base = (size_t)(b * NCH + c) * CSTRIDE + (size_t)q * 16 * NFR;
  float acc[4] = {0.f, 0.f, 0.f, 0.f};
  for (int ff = 0; ff < 16; ++ff) {
    #pragma unroll
    for (int k = 0; k < 4; ++k) {
      const int n = threadIdx.x + 256 * k;
      if (n < NFR) {
        const float r = Y[base + (size_t)ff * NFR + n];
        const float i = Y[base + (size_t)ff * NFR + n + PLANE];
        acc[k] = fmaf(r, r, acc[k]);
        acc[k] = fmaf(i, i, acc[k]);
      }
    }
  }
  #pragma unroll
  for (int k = 0; k < 4; ++k) {
    const int n = threadIdx.x + 256 * k;
    if (n < NFR) part[((size_t)(b * NCH + c) * 32 + q) * NFR + n] = acc[k];
  }
}

// ---- B2: sumf[b*4000 + c*1000 + n] = sum_q part ----
__global__ __launch_bounds__(256, 4)
void finish_sumf(const float* __restrict__ part, float* __restrict__ sumf)
{
  const int o = blockIdx.x * 256 + threadIdx.x;
  if (o < 8000) {
    const int b = o / 4000;
    const int rem = o - b * 4000;
    const int c = rem / 1000;
    const int n = rem - c * 1000;
    const float* p = part + ((size_t)(b * NCH + c) * 32) * NFR + n;
    float s = 0.f;
    for (int q = 0; q < 32; ++q) s += p[(size_t)q * NFR];
    sumf[o] = s;
  }
}

// ---- stage C: one full iteration for one (b,f) slice — TWO waves ----
// wave wid owns slots s=0..7: frame n = 512*wid + 64*s + lane
__global__ __launch_bounds__(128, 2)
void iter_c(const float* __restrict__ Xr, const float* __restrict__ Xi,
            float* __restrict__ Y, const float* __restrict__ sumf)
{
  __shared__ float xre[NCH][NFR];
  __shared__ float xim[NCH][NFR];
  __shared__ float red[2][2][12];   // [parity][wave][12]
  __shared__ float gred[2][4];

  const int tid  = threadIdx.x;
  const int lane = tid & 63;
  const int wid  = tid >> 6;
  const int ow   = wid ^ 1;
  const int bf   = blockIdx.x, b = bf >> 9, f = bf & 511;
  const size_t base = ((size_t)b * NCH * NFQ + f) * NFR;
  const int nb = 512 * wid + lane;          // frame of slot 0

  // ---- stage X into LDS (float4 both sides; conflict-free reads later) ----
  for (int j = tid; j < NCH * 250; j += 128) {
    const int c = j / 250, q = j - c * 250;
    *(float4*)(&xre[c][4*q]) = *(const float4*)(Xr + base + (size_t)c*CSTRIDE + 4*q);
    *(float4*)(&xim[c][4*q]) = *(const float4*)(Xi + base + (size_t)c*CSTRIDE + 4*q);
  }

  // ---- sumf -> g (cross-wave via gred), weights w ----
  float w[8][4];
  {
    float sfr[8][4];
    const float* sfb = sumf + b * 4000;
    #pragma unroll
    for (int s = 0; s < 8; ++s) {
      const int na = min(nb + 64*s, 999);
      #pragma unroll
      for (int c = 0; c < 4; ++c) sfr[s][c] = sfb[c*1000 + na];
    }
    float gp[4] = {0.f, 0.f, 0.f, 0.f};
    #pragma unroll
    for (int s = 0; s < 8; ++s) {
      const bool valid = (nb + 64*s) < NFR;
      #pragma unroll
      for (int c = 0; c < 4; ++c) gp[c] += valid ? sfr[s][c] : 0.f;
    }
    #pragma unroll
    for (int c = 0; c < 4; ++c) gp[c] = wave_red(gp[c]);
    if (lane == 0) {
      #pragma unroll
      for (int c = 0; c < 4; ++c) gred[wid][c] = gp[c];
    }
    __syncthreads();                        // also orders X staging

    float g[4];
    #pragma unroll
    for (int c = 0; c < 4; ++c)
      g[c] = fmaxf((gred[0][c] + gred[1][c]) * INVFN, EPSV);

    // w = g / max(2*sqrt(s), 1e-5)  ==  g * min(0.5*rsqrt(s), 1e5)
    #pragma unroll
    for (int s = 0; s < 8; ++s) {
      const bool valid = (nb + 64*s) < NFR;
      #pragma unroll
      for (int c = 0; c < 4; ++c)
        w[s][c] = valid ? g[c] * fminf(0.5f * fast_rsq(sfr[s][c]), 1e5f) : 0.f;
    }

    // ---- load Y and normalize (invgs = rsqrt(g)) ----
    float invgs[4];
    #pragma unroll
    for (int c = 0; c < 4; ++c) invgs[c] = fast_rsq(g[c]);
    // (fall through into y load below using invgs)
    #pragma unroll
    for (int c = 0; c < 4; ++c) w[0][c] *= 1.0f;  // keep w live (no-op)
    // Y load:
    // declared outside this scope? no — declare y here and use throughout
    // (see below: y declared after to keep scope flat)
    // -- handled right after this block --
    #pragma unroll
    for (int c = 0; c < 4; ++c) gred[0][c] = invgs[c] * 0.f + gred[0][c]; // no-op
    // stash invgs in registers via variables declared below
    // (we simply recompute: cheap, 4 rsq)
  }

  float invgs[4];
  {
    float g2[4];
    #pragma unroll
    for (int c = 0; c < 4; ++c)
      g2[c] = fmaxf((gred[0][c] + gred[1][c]) * INVFN, EPSV);
    #pragma unroll
    for (int c = 0; c < 4; ++c) invgs[c] = fast_rsq(g2[c]);
  }

  float yre[8][4], yim[8][4];
  #pragma unroll
  for (int s = 0; s < 8; ++s) {
    const int na = min(nb + 64*s, 999);
    #pragma unroll
    for (int c = 0; c < 4; ++c) {
      yre[s][c] = Y[base + (size_t)c*CSTRIDE + na] * invgs[c];
      yim[s][c] = Y[base + (size_t)c*CSTRIDE + na + PLANE] * invgs[c];
    }
  }

  int par = 0;
  float p[12], vr_[4], vi_[4];

  // ----- 4 source stages -----
  #pragma unroll
  for (int src = 0; src < 4; ++src) {
    #pragma unroll
    for (int j = 0; j < 12; ++j) p[j] = 0.f;
    #pragma unroll
    for (int s = 0; s < 8; ++s) {
      const float zr = yre[s][src], zi = yim[s][src];
      const float zz = zr*zr + zi*zi;
      #pragma unroll
      for (int c = 0; c < 4; ++c) {
        const float wk = w[s][c];
        p[8+c] = fmaf(wk, zz, p[8+c]);
        if (c != src) {                      // p[src], p[4+src] are dead
          p[c]   = fmaf(wk, yre[s][c]*zr + yim[s][c]*zi, p[c]);
          p[4+c] = fmaf(wk, yim[s][c]*zr - yre[s][c]*zi, p[4+c]);
        }
      }
    }
    #pragma unroll
    for (int j = 0; j < 12; ++j)
      if (j != src && j != 4 + src) p[j] = wave_red(p[j]);
    if (lane == 0) {
      #pragma unroll
      for (int j = 0; j < 12; ++j) red[par][wid][j] = p[j];
    }
    __syncthreads();
    #pragma unroll
    for (int j = 0; j < 12; ++j) p[j] += red[par][ow][j];
    par ^= 1;

    float vd[4];
    #pragma unroll
    for (int c = 0; c < 4; ++c) vd[c] = fmaxf(p[8+c] * INVNF, EPSV);
    #pragma unroll
    for (int c = 0; c < 4; ++c) {
      const float inv = INVNF * fast_rcp(vd[c]);
      vr_[c] = p[c] * inv;  vi_[c] = p[4+c] * inv;
    }
    vr_[src] = 1.0f - fast_rsq(vd[src]);  vi_[src] = 0.0f;

    #pragma unroll
    for (int s = 0; s < 8; ++s) {
      const float zr = yre[s][src], zi = yim[s][src];
      #pragma unroll
      for (int c = 0; c < 4; ++c) {
        yre[s][c] -= vr_[c]*zr - vi_[c]*zi;
        yim[s][c] -= vr_[c]*zi + vi_[c]*zr;
      }
    }
  }

  // ----- 20 dereverb stages: z = X[src][n + tap - 6] from LDS -----
  for (int src = 0; src < 4; ++src) {
    const float* px = xre[src];
    const float* py = xim[src];
    #pragma unroll
    for (int tap = 0; tap < 5; ++tap) {
      const int off = tap - 6;               // -6..-2
      float zr[8], zi[8];
      #pragma unroll
      for (int s = 0; s < 8; ++s) {
        const int n = nb + 64*s;
        const int m = n + off;
        const bool ok = (n < NFR) && (m >= 0);
        zr[s] = ok ? px[m] : 0.f;
        zi[s] = ok ? py[m] : 0.f;
      }

      #pragma unroll
      for (int j = 0; j < 12; ++j) p[j] = 0.f;
      #pragma unroll
      for (int s = 0; s < 8; ++s) {
        const float zz = zr[s]*zr[s] + zi[s]*zi[s];
        #pragma unroll
        for (int c = 0; c < 4; ++c) {
          const float wk = w[s][c];
          p[8+c] = fmaf(wk, zz, p[8+c]);
          p[c]   = fmaf(wk, yre[s][c]*zr[s] + yim[s][c]*zi[s], p[c]);
          p[4+c] = fmaf(wk, yim[s][c]*zr[s] - yre[s][c]*zi[s], p[4+c]);
        }
      }
      #pragma unroll
      for (int j = 0; j < 12; ++j) p[j] = wave_red(p[j]);
      if (lane == 0) {
        #pragma unroll
        for (int j = 0; j < 12; ++j) red[par][wid][j] = p[j];
      }
      __syncthreads();
      #pragma unroll
      for (int j = 0; j < 12; ++j) p[j] += red[par][ow][j];
      par ^= 1;

      #pragma unroll
      for (int c = 0; c < 4; ++c) {          // dereverb: no inv_nf (matches ref)
        const float inv = fast_rcp(fmaxf(p[8+c], EPSV));
        vr_[c] = p[c] * inv;  vi_[c] = p[4+c] * inv;
      }
      #pragma unroll
      for (int s = 0; s < 8; ++s) {
        #pragma unroll
        for (int c = 0; c < 4; ++c) {
          yre[s][c] -= vr_[c]*zr[s] - vi_[c]*zi[s];
          yim[s][c] -= vr_[c]*zi[s] + vi_[c]*zr[s];
        }
      }
    }
  }

  // ---- write back Y (layout == final output layout) ----
  #pragma unroll
  for (int s = 0; s < 8; ++s) {
    const int n = nb + 64*s;
    if (n < NFR) {
      #pragma unroll
      for (int c = 0; c < 4; ++c) {
        Y[base + (size_t)c*CSTRIDE + n]         = yre[s][c];
        Y[base + (size_t)c*CSTRIDE + n + PLANE] = yim[s][c];
      }
    }
  }
}

extern "C" void kernel_launch(void* const* d_in, const int* in_sizes, int n_in,
                              void* d_out, int out_size, void* d_ws, size_t ws_size,
                              hipStream_t stream)
{
  const float* Xr = (const float*)d_in[0];
  const float* Xi = (const float*)d_in[1];
  float* Y = (float*)d_out;                 // Yr | Yi, final layout
  float* part = (float*)d_ws;               // 256,000 floats
  float* sumf = part + 256000;              // 8,000 floats

  init_y<<<1024, 256, 0, stream>>>(Xr, Xi, Y);
  for (int it = 0; it < NIT; ++it) {
    partial_sumf<<<256, 256, 0, stream>>>(Y, part);
    finish_sumf<<<32, 256, 0, stream>>>(part, sumf);
    iter_c<<<1024, 128, 0, stream>>>(Xr, Xi, Y, sumf);
  }
}

// Round 8
// 369.065 us; speedup vs baseline: 1.9575x; 1.1650x over previous
//
#include <hip/hip_runtime.h>

// OverISS-T  (input (2,4,512,1000) complex, 5 iterations)
// Multi-kernel, stream-ordered. Y state lives in d_out (Yr | Yi planes, final
// output layout). W/H are dead state w.r.t. Y — skipped.
//
// Round 8 (base = R7: 2-wave iter_c, DPP reductions, 0 bank conflicts):
//  A) |Y|^2 mag plane written in init_y/iter_c epilogues (Y already in regs);
//     f-reduction reads the 16MB mag plane instead of re-reading 33MB of Y.
//     Falls back to the R7 Y-reading reduction if ws_size is too small.
//  B) dereverb: per-src register tap-window xw[8][5] (taps are 5 consecutive
//     frames per slot) -> taps become pure-register FMA; edge clamps only in
//     the compile-time s=0 / s=7 slices.

constexpr int NCH = 4;
constexpr int NFQ = 512;
constexpr int NFR = 1000;
constexpr int NIT = 5;
constexpr float EPSV  = 1e-3f;
constexpr float INVNF = 1.0f / 1000.0f;
constexpr float INVFN = 1.0f / (512.0f * 1000.0f);
constexpr size_t PLANE = 4096000;             // 2*4*512*1000
constexpr size_t CSTRIDE = (size_t)NFQ * NFR; // 512000

__device__ __forceinline__ float fast_rcp(float x) { return __builtin_amdgcn_rcpf(x); }
__device__ __forceinline__ float fast_rsq(float x) { return __builtin_amdgcn_rsqf(x); }

template <int CTRL>
__device__ __forceinline__ float dpp_add(float x) {
  return x + __int_as_float(__builtin_amdgcn_update_dpp(
      0, __float_as_int(x), CTRL, 0xF, 0xF, true));
}
__device__ __forceinline__ float wave_red(float x) {
  x = dpp_add<0xB1>(x);    // quad_perm [1,0,3,2]
  x = dpp_add<0x4E>(x);    // quad_perm [2,3,0,1]
  x = dpp_add<0x141>(x);   // row_half_mirror
  x = dpp_add<0x140>(x);   // row_mirror
  x = dpp_add<0x142>(x);   // row_bcast15
  x = dpp_add<0x143>(x);   // row_bcast31
  return __int_as_float(__builtin_amdgcn_readlane(__float_as_int(x), 63));
}

// ---- Y0 = 0.999*X[c] + 0.001*sum_d X[d];  optional |Y0|^2 plane ----
__global__ __launch_bounds__(256, 4)
void init_y(const float* __restrict__ Xr, const float* __restrict__ Xi,
            float* __restrict__ Y, float* __restrict__ mag)
{
  const int bf = blockIdx.x, b = bf >> 9, f = bf & 511;
  const size_t base = ((size_t)b * NCH * NFQ + f) * NFR;
  const int tid = threadIdx.x;
  if (tid < 250) {
    const int nq = 4 * tid;
    float4 xr[4], xi[4];
    #pragma unroll
    for (int c = 0; c < 4; ++c) {
      xr[c] = *(const float4*)(Xr + base + (size_t)c * CSTRIDE + nq);
      xi[c] = *(const float4*)(Xi + base + (size_t)c * CSTRIDE + nq);
    }
    float4 sr, si;
    sr.x = xr[0].x+xr[1].x+xr[2].x+xr[3].x;  si.x = xi[0].x+xi[1].x+xi[2].x+xi[3].x;
    sr.y = xr[0].y+xr[1].y+xr[2].y+xr[3].y;  si.y = xi[0].y+xi[1].y+xi[2].y+xi[3].y;
    sr.z = xr[0].z+xr[1].z+xr[2].z+xr[3].z;  si.z = xi[0].z+xi[1].z+xi[2].z+xi[3].z;
    sr.w = xr[0].w+xr[1].w+xr[2].w+xr[3].w;  si.w = xi[0].w+xi[1].w+xi[2].w+xi[3].w;
    #pragma unroll
    for (int c = 0; c < 4; ++c) {
      float4 yr, yi;
      yr.x = 0.999f*xr[c].x + 0.001f*sr.x;  yi.x = 0.999f*xi[c].x + 0.001f*si.x;
      yr.y = 0.999f*xr[c].y + 0.001f*sr.y;  yi.y = 0.999f*xi[c].y + 0.001f*si.y;
      yr.z = 0.999f*xr[c].z + 0.001f*sr.z;  yi.z = 0.999f*xi[c].z + 0.001f*si.z;
      yr.w = 0.999f*xr[c].w + 0.001f*sr.w;  yi.w = 0.999f*xi[c].w + 0.001f*si.w;
      *(float4*)(Y + base + (size_t)c * CSTRIDE + nq)         = yr;
      *(float4*)(Y + base + (size_t)c * CSTRIDE + nq + PLANE) = yi;
      if (mag) {
        float4 m;
        m.x = yr.x*yr.x + yi.x*yi.x;  m.y = yr.y*yr.y + yi.y*yi.y;
        m.z = yr.z*yr.z + yi.z*yi.z;  m.w = yr.w*yr.w + yi.w*yi.w;
        *(float4*)(mag + base + (size_t)c * CSTRIDE + nq) = m;
      }
    }
  }
}

// ---- mag reduction over f, stage 1: 32-f chunks (128 blocks) ----
__global__ __launch_bounds__(256, 4)
void partial_mag(const float* __restrict__ mag, float* __restrict__ part2)
{
  const int id = blockIdx.x;                  // b | c | k
  const int k = id & 15, c = (id >> 4) & 3, b = id >> 6;
  const int tid = threadIdx.x;
  if (tid < 250) {
    const int nq = 4 * tid;
    const float* base = mag + ((size_t)((b*4+c)*NFQ + k*32)) * NFR + nq;
    float4 acc = make_float4(0.f, 0.f, 0.f, 0.f);
    for (int ff = 0; ff < 32; ++ff) {
      const float4 v = *(const float4*)(base + (size_t)ff * NFR);
      acc.x += v.x; acc.y += v.y; acc.z += v.z; acc.w += v.w;
    }
    *(float4*)(part2 + ((size_t)((b*4+c)*16 + k)) * NFR + nq) = acc;
  }
}

// ---- mag reduction stage 2 ----
__global__ __launch_bounds__(256, 4)
void finish_mag(const float* __restrict__ part2, float* __restrict__ sumf)
{
  const int t = blockIdx.x * 256 + threadIdx.x;   // 8 blocks, 2000 quads
  if (t < 2000) {
    const int b = t / 1000, r = t - 1000 * b;
    const int c = r / 250,  qn = r - 250 * c;
    const float* base = part2 + ((size_t)((b*4+c)*16)) * NFR + 4*qn;
    float4 acc = make_float4(0.f, 0.f, 0.f, 0.f);
    #pragma unroll
    for (int k = 0; k < 16; ++k) {
      const float4 v = *(const float4*)(base + (size_t)k * NFR);
      acc.x += v.x; acc.y += v.y; acc.z += v.z; acc.w += v.w;
    }
    *(float4*)(sumf + (size_t)b*4000 + c*1000 + 4*qn) = acc;
  }
}

// ---- legacy sumf path (reads Y) — fallback when ws is small ----
__global__ __launch_bounds__(256, 4)
void partial_sumf(const float* __restrict__ Y, float* __restrict__ part)
{
  const int id = blockIdx.x;                 // b | c | q
  const int q = id & 31, c = (id >> 5) & 3, b = id >> 7;
  const size_t base = (size_t)(b * NCH + c) * CSTRIDE + (size_t)q * 16 * NFR;
  float acc[4] = {0.f, 0.f, 0.f, 0.f};
  for (int ff = 0; ff < 16; ++ff) {
    #pragma unroll
    for (int k = 0; k < 4; ++k) {
      const int n = threadIdx.x + 256 * k;
      if (n < NFR) {
        const float r = Y[base + (size_t)ff * NFR + n];
        const float i = Y[base + (size_t)ff * NFR + n + PLANE];
        acc[k] = fmaf(r, r, acc[k]);
        acc[k] = fmaf(i, i, acc[k]);
      }
    }
  }
  #pragma unroll
  for (int k = 0; k < 4; ++k) {
    const int n = threadIdx.x + 256 * k;
    if (n < NFR) part[((size_t)(b * NCH + c) * 32 + q) * NFR + n] = acc[k];
  }
}
__global__ __launch_bounds__(256, 4)
void finish_sumf(const float* __restrict__ part, float* __restrict__ sumf)
{
  const int o = blockIdx.x * 256 + threadIdx.x;
  if (o < 8000) {
    const int b = o / 4000;
    const int rem = o - b * 4000;
    const int c = rem / 1000;
    const int n = rem - c * 1000;
    const float* p = part + ((size_t)(b * NCH + c) * 32) * NFR + n;
    float s = 0.f;
    for (int q = 0; q < 32; ++q) s += p[(size_t)q * NFR];
    sumf[o] = s;
  }
}

// ---- stage C: one full iteration for one (b,f) slice — TWO waves ----
// wave wid owns slots s=0..7: frame n = 512*wid + 64*s + lane
__global__ __launch_bounds__(128, 2)
void iter_c(const float* __restrict__ Xr, const float* __restrict__ Xi,
            float* __restrict__ Y, const float* __restrict__ sumf,
            float* __restrict__ mag)
{
  __shared__ float xre[NCH][NFR];
  __shared__ float xim[NCH][NFR];
  __shared__ float red[2][2][12];   // [parity][wave][12]
  __shared__ float gred[2][4];

  const int tid  = threadIdx.x;
  const int lane = tid & 63;
  const int wid  = tid >> 6;
  const int ow   = wid ^ 1;
  const int bf   = blockIdx.x, b = bf >> 9, f = bf & 511;
  const size_t base = ((size_t)b * NCH * NFQ + f) * NFR;
  const int nb = 512 * wid + lane;          // frame of slot 0

  // ---- stage X into LDS (float4 both sides) ----
  for (int j = tid; j < NCH * 250; j += 128) {
    const int c = j / 250, q = j - c * 250;
    *(float4*)(&xre[c][4*q]) = *(const float4*)(Xr + base + (size_t)c*CSTRIDE + 4*q);
    *(float4*)(&xim[c][4*q]) = *(const float4*)(Xi + base + (size_t)c*CSTRIDE + 4*q);
  }

  // ---- sumf -> g (cross-wave via gred), invgs, weights w ----
  float w[8][4], invgs[4];
  {
    float sfr[8][4];
    const float* sfb = sumf + b * 4000;
    #pragma unroll
    for (int s = 0; s < 8; ++s) {
      const int na = min(nb + 64*s, 999);
      #pragma unroll
      for (int c = 0; c < 4; ++c) sfr[s][c] = sfb[c*1000 + na];
    }
    float gp[4] = {0.f, 0.f, 0.f, 0.f};
    #pragma unroll
    for (int s = 0; s < 8; ++s) {
      const bool valid = (nb + 64*s) < NFR;
      #pragma unroll
      for (int c = 0; c < 4; ++c) gp[c] += valid ? sfr[s][c] : 0.f;
    }
    #pragma unroll
    for (int c = 0; c < 4; ++c) gp[c] = wave_red(gp[c]);
    if (lane == 0) {
      #pragma unroll
      for (int c = 0; c < 4; ++c) gred[wid][c] = gp[c];
    }
    __syncthreads();                        // also orders X staging

    #pragma unroll
    for (int c = 0; c < 4; ++c) {
      const float g = fmaxf((gred[0][c] + gred[1][c]) * INVFN, EPSV);
      invgs[c] = fast_rsq(g);               // sqrt(g) >= sqrt(1e-3) > EPS
      // w = g / max(2*sqrt(s), 1e-5)  ==  g * min(0.5*rsqrt(s), 1e5)
      #pragma unroll
      for (int s = 0; s < 8; ++s) {
        const bool valid = (nb + 64*s) < NFR;
        w[s][c] = valid ? g * fminf(0.5f * fast_rsq(sfr[s][c]), 1e5f) : 0.f;
      }
    }
  }

  // ---- load Y, normalize ----
  float yre[8][4], yim[8][4];
  #pragma unroll
  for (int s = 0; s < 8; ++s) {
    const int na = min(nb + 64*s, 999);
    #pragma unroll
    for (int c = 0; c < 4; ++c) {
      yre[s][c] = Y[base + (size_t)c*CSTRIDE + na] * invgs[c];
      yim[s][c] = Y[base + (size_t)c*CSTRIDE + na + PLANE] * invgs[c];
    }
  }

  int par = 0;
  float p[12], vr_[4], vi_[4];

  // ----- 4 source stages -----
  #pragma unroll
  for (int src = 0; src < 4; ++src) {
    #pragma unroll
    for (int j = 0; j < 12; ++j) p[j] = 0.f;
    #pragma unroll
    for (int s = 0; s < 8; ++s) {
      const float zr = yre[s][src], zi = yim[s][src];
      const float zz = zr*zr + zi*zi;
      #pragma unroll
      for (int c = 0; c < 4; ++c) {
        const float wk = w[s][c];
        p[8+c] = fmaf(wk, zz, p[8+c]);
        if (c != src) {                      // p[src], p[4+src] are dead
          p[c]   = fmaf(wk, yre[s][c]*zr + yim[s][c]*zi, p[c]);
          p[4+c] = fmaf(wk, yim[s][c]*zr - yre[s][c]*zi, p[4+c]);
        }
      }
    }
    #pragma unroll
    for (int j = 0; j < 12; ++j)
      if (j != src && j != 4 + src) p[j] = wave_red(p[j]);
    if (lane == 0) {
      #pragma unroll
      for (int j = 0; j < 12; ++j) red[par][wid][j] = p[j];
    }
    __syncthreads();
    #pragma unroll
    for (int j = 0; j < 12; ++j) p[j] += red[par][ow][j];
    par ^= 1;

    float vd[4];
    #pragma unroll
    for (int c = 0; c < 4; ++c) vd[c] = fmaxf(p[8+c] * INVNF, EPSV);
    #pragma unroll
    for (int c = 0; c < 4; ++c) {
      const float inv = INVNF * fast_rcp(vd[c]);
      vr_[c] = p[c] * inv;  vi_[c] = p[4+c] * inv;
    }
    vr_[src] = 1.0f - fast_rsq(vd[src]);  vi_[src] = 0.0f;

    #pragma unroll
    for (int s = 0; s < 8; ++s) {
      const float zr = yre[s][src], zi = yim[s][src];
      #pragma unroll
      for (int c = 0; c < 4; ++c) {
        yre[s][c] -= vr_[c]*zr - vi_[c]*zi;
        yim[s][c] -= vr_[c]*zi + vi_[c]*zr;
      }
    }
  }

  // ----- 20 dereverb stages via per-src register tap-window -----
  // xw[s][o] = X[src][nb + 64*s - 6 + o], o=0..4; tap t reads xw[s][t].
  for (int src = 0; src < 4; ++src) {
    const float* px = xre[src];
    const float* py = xim[src];
    float xwr[8][5], xwi[8][5];
    #pragma unroll
    for (int s = 0; s < 8; ++s) {
      #pragma unroll
      for (int o = 0; o < 5; ++o) {
        const int m = nb + 64*s - 6 + o;
        int mc = m;
        if (s == 0) mc = max(m, 0);         // only slice where m can be < 0
        if (s == 7) mc = min(m, 999);       // only slice where m can be > 999
        float vr = px[mc], vi = py[mc];
        if (s == 0) {                        // zero the pre-signal taps
          vr = (m >= 0) ? vr : 0.f;
          vi = (m >= 0) ? vi : 0.f;
        }
        xwr[s][o] = vr; xwi[s][o] = vi;      // n>=NFR slots masked by w=0
      }
    }

    #pragma unroll
    for (int tap = 0; tap < 5; ++tap) {
      #pragma unroll
      for (int j = 0; j < 12; ++j) p[j] = 0.f;
      #pragma unroll
      for (int s = 0; s < 8; ++s) {
        const float zr = xwr[s][tap], zi = xwi[s][tap];
        const float zz = zr*zr + zi*zi;
        #pragma unroll
        for (int c = 0; c < 4; ++c) {
          const float wk = w[s][c];
          p[8+c] = fmaf(wk, zz, p[8+c]);
          p[c]   = fmaf(wk, yre[s][c]*zr + yim[s][c]*zi, p[c]);
          p[4+c] = fmaf(wk, yim[s][c]*zr - yre[s][c]*zi, p[4+c]);
        }
      }
      #pragma unroll
      for (int j = 0; j < 12; ++j) p[j] = wave_red(p[j]);
      if (lane == 0) {
        #pragma unroll
        for (int j = 0; j < 12; ++j) red[par][wid][j] = p[j];
      }
      __syncthreads();
      #pragma unroll
      for (int j = 0; j < 12; ++j) p[j] += red[par][ow][j];
      par ^= 1;

      #pragma unroll
      for (int c = 0; c < 4; ++c) {          // dereverb: no inv_nf (matches ref)
        const float inv = fast_rcp(fmaxf(p[8+c], EPSV));
        vr_[c] = p[c] * inv;  vi_[c] = p[4+c] * inv;
      }
      #pragma unroll
      for (int s = 0; s < 8; ++s) {
        const float zr = xwr[s][tap], zi = xwi[s][tap];
        #pragma unroll
        for (int c = 0; c < 4; ++c) {
          yre[s][c] -= vr_[c]*zr - vi_[c]*zi;
          yim[s][c] -= vr_[c]*zi + vi_[c]*zr;
        }
      }
    }
  }

  // ---- write back Y (+ optional |Y|^2 plane; same indexing as Y) ----
  #pragma unroll
  for (int s = 0; s < 8; ++s) {
    const int n = nb + 64*s;
    if (n < NFR) {
      #pragma unroll
      for (int c = 0; c < 4; ++c) {
        const float yr = yre[s][c], yi = yim[s][c];
        Y[base + (size_t)c*CSTRIDE + n]         = yr;
        Y[base + (size_t)c*CSTRIDE + n + PLANE] = yi;
        if (mag) mag[base + (size_t)c*CSTRIDE + n] = yr*yr + yi*yi;
      }
    }
  }
}

extern "C" void kernel_launch(void* const* d_in, const int* in_sizes, int n_in,
                              void* d_out, int out_size, void* d_ws, size_t ws_size,
                              hipStream_t stream)
{
  const float* Xr = (const float*)d_in[0];
  const float* Xi = (const float*)d_in[1];
  float* Y = (float*)d_out;                 // Yr | Yi, final layout

  const bool big_ws = ws_size >= (size_t)(4096000 + 128000 + 8000) * 4;
  if (big_ws) {
    float* mag   = (float*)d_ws;            // 4,096,000 floats
    float* part2 = mag + 4096000;           // 128,000
    float* sumf  = part2 + 128000;          // 8,000
    init_y<<<1024, 256, 0, stream>>>(Xr, Xi, Y, mag);
    for (int it = 0; it < NIT; ++it) {
      partial_mag<<<128, 256, 0, stream>>>(mag, part2);
      finish_mag<<<8, 256, 0, stream>>>(part2, sumf);
      // last iteration: nobody consumes mag afterwards -> skip the extra write
      iter_c<<<1024, 128, 0, stream>>>(Xr, Xi, Y, sumf,
                                       (it < NIT - 1) ? mag : nullptr);
    }
  } else {
    float* part = (float*)d_ws;             // 256,000 floats
    float* sumf = part + 256000;            // 8,000
    init_y<<<1024, 256, 0, stream>>>(Xr, Xi, Y, nullptr);
    for (int it = 0; it < NIT; ++it) {
      partial_sumf<<<256, 256, 0, stream>>>(Y, part);
      finish_sumf<<<32, 256, 0, stream>>>(part, sumf);
      iter_c<<<1024, 128, 0, stream>>>(Xr, Xi, Y, sumf, nullptr);
    }
  }
}